// Round 14
// baseline (254.955 us; speedup 1.0000x reference)
//
#include <hip/hip_runtime.h>
#include <hip/hip_bf16.h>
#include <math.h>

// Problem dims
#define BB 8
#define TT 16
#define HH 112
#define WW 112
#define CC 3
#define FF 16
#define HP 56
#define WP 56
#define HO 54
#define WO 54
#define NC 6

#define NPIX (BB*HO*WO)               // 23328
#define SPIX (HO*WO)                  // 2916
#define POOLED_BF16  (128*56*56*16)   // 6,422,528 bf16

// xpad: per-frame bf16 rows with halo + pad: 118 rows x 360 elems
#define XROW 360
#define XFRM (118*XROW)               // 42,480
#define XPAD_ELEMS (128*XFRM)         // 5,437,440 per parity copy

typedef __attribute__((ext_vector_type(8))) short s8v;   // 8 bf16 (4 VGPRs)
typedef __attribute__((ext_vector_type(4))) float f4v;   // MFMA acc

__device__ __forceinline__ float hsig(float x) {
    return fminf(fmaxf(0.2f*x + 0.5f, 0.0f), 1.0f);
}
__device__ __forceinline__ unsigned pk2(float lo, float hi) {
    union { __hip_bfloat16 h; unsigned short u; } a, b;
    a.h = __float2bfloat16(lo); b.h = __float2bfloat16(hi);
    return ((unsigned)b.u << 16) | (unsigned)a.u;
}
__device__ __forceinline__ float bf2f(unsigned short u) {
    union { unsigned v; float f; } x; x.v = ((unsigned)u) << 16; return x.f;
}
__device__ __forceinline__ unsigned short f2bfu(float f) {
    union { __hip_bfloat16 h; unsigned short u; } v;
    v.h = __float2bfloat16(f); return v.u;
}

// ---------- prep job bodies (verbatim logic, virtual block id) ----------
__device__ __forceinline__ void w_prepack_body(int vb, const float* __restrict__ w,
                                               __hip_bfloat16* __restrict__ wb)
{
    int i = vb * 256 + threadIdx.x;                // 40*256 = 10240 exact
    int j    = i & 7;
    int lane = (i >> 3) & 63;
    int ks   = (i >> 9) % 5;
    int nt   = (i >> 9) / 5;
    int k = ks*32 + ((lane >> 4) & 3)*8 + j;
    int n = nt*16 + (lane & 15);
    float v = 0.f;
    if (k < 144) {
        int tap = k >> 4, ci = k & 15;
        v = w[tap*1024 + ci*64 + n];
    }
    wb[i] = __float2bfloat16(v);
}

__device__ __forceinline__ void cw_prepack_body(int vb, const float* __restrict__ cw,
                                                __hip_bfloat16* __restrict__ cwb)
{
    int i = vb * 256 + threadIdx.x;                // 12*256 = 3072 exact
    int j    = i & 7;
    int lane = (i >> 3) & 63;
    int ks   = i >> 9;                             // 0..5
    int k = ks*32 + ((lane >> 4) & 3)*8 + j;
    int n = lane & 15;
    float v = 0.f;
    if (k < 168) {
        int row = k / 24, idx = k % 24;
        if (idx < 21) {
            int kx = idx / 3, ci = idx % 3;
            v = cw[((row*7 + kx)*3 + ci)*16 + n];
        }
    }
    cwb[i] = __float2bfloat16(v);
}

__device__ __forceinline__ void xpad_body(int vb, const float* __restrict__ x,
                                          __hip_bfloat16* __restrict__ xp0,
                                          __hip_bfloat16* __restrict__ xp1)
{
    int idx = vb * 256 + threadIdx.x;              // 5310*256 = 1,359,360 exact
    int e4 = idx % 90;
    int rr = (idx / 90) % 118;
    int fr = idx / (90*118);
    int e0 = e4 * 4;
    int ir = rr - 3;
    const float* xf = x + (size_t)fr * (112*336);
    bool rowok = (ir >= 0) & (ir < 112);

    float v[5];
    #pragma unroll
    for (int i = 0; i < 5; ++i) {
        int s = e0 - 1 + i;
        bool ok = rowok & (s >= 9) & (s < 345);
        v[i] = ok ? xf[ir*336 + (s - 9)] : 0.f;
    }
    size_t o = ((size_t)fr*118 + rr) * XROW + e0;
    uint2 a0, a1;
    a0.x = pk2(v[1], v[2]); a0.y = pk2(v[3], v[4]);
    a1.x = pk2(v[0], v[1]); a1.y = pk2(v[2], v[3]);
    *(uint2*)&xp0[o] = a0;
    *(uint2*)&xp1[o] = a1;
}

// Kernel 0 (R26, kept): ALL independent prep work in ONE dispatch.
__global__ __launch_bounds__(256) void prep_kernel(
    const float* __restrict__ x,
    __hip_bfloat16* __restrict__ xp0, __hip_bfloat16* __restrict__ xp1,
    const float* __restrict__ wk, __hip_bfloat16* __restrict__ wkb,
    const float* __restrict__ wr, __hip_bfloat16* __restrict__ wrb,
    const float* __restrict__ cw, __hip_bfloat16* __restrict__ cwb,
    float* __restrict__ cpl, __hip_bfloat16* __restrict__ hA)
{
    int bid = blockIdx.x;
    if (bid < 5310) { xpad_body(bid, x, xp0, xp1); return; }
    bid -= 5310;
    if (bid < 40) { w_prepack_body(bid, wk, wkb); return; }
    bid -= 40;
    if (bid < 40) { w_prepack_body(bid, wr, wrb); return; }
    bid -= 40;
    if (bid < 12) { cw_prepack_body(bid, cw, cwb); return; }
    bid -= 12;
    if (bid < 365) {                               // c0 = 0
        int u = bid*256 + threadIdx.x;
        if (u < 93312) ((uint4*)cpl)[u] = (uint4){0,0,0,0};
        return;
    }
    bid -= 365;
    {                                              // h0 = 0
        int u = bid*256 + threadIdx.x;
        if (u < 46656) ((uint4*)hA)[u] = (uint4){0,0,0,0};
    }
}

// Kernel 1: conv 7x7 + bias + relu + maxpool via MFMA.
// R20: LDS-staged input rows (verified win: 47.6 -> ~15 us).
__global__ __launch_bounds__(256, 6) void conv_mfma_kernel(
    const __hip_bfloat16* __restrict__ xp0,
    const __hip_bfloat16* __restrict__ xp1,
    const __hip_bfloat16* __restrict__ cwb,  // [6][64][8]
    const float* __restrict__ cb,            // [16]
    __hip_bfloat16* __restrict__ pooled)     // [128,56,56,16] bf16
{
    int wv = threadIdx.x >> 6;
    int lane = threadIdx.x & 63;
    int quad = lane >> 4;
    int fr = blockIdx.y;
    int p0b = blockIdx.x * 64;               // block's pooled px base
    int p0 = p0b + wv * 16;                  // wave's pooled px base

    __shared__ short lx[2][10][368];         // 14,720 B
    int pr0 = p0b / 56;
    int ohb = 2 * pr0;                       // first staged input row
    {
        const __hip_bfloat16* s0 = xp0 + (size_t)fr*XFRM + (size_t)ohb*XROW;
        const __hip_bfloat16* s1 = xp1 + (size_t)fr*XFRM + (size_t)ohb*XROW;
        for (int u = threadIdx.x; u < 900; u += 256) {
            int par = u / 450;
            int rem = u - par*450;
            int rr  = rem / 45;
            int c   = rem - rr*45;           // 16B unit within row
            const __hip_bfloat16* s = (par ? s1 : s0) + rr*XROW + c*8;
            *(uint4*)&lx[par][rr][c*8] = *(const uint4*)s;
        }
    }
    __syncthreads();

    const s8v* wbp = (const s8v*)cwb;
    s8v bfrag[6];
    #pragma unroll
    for (int ks = 0; ks < 6; ++ks) bfrag[ks] = wbp[ks*64 + lane];

    const unsigned* lx32 = (const unsigned*)&lx[0][0][0];

    f4v acc[4];
    #pragma unroll
    for (int j = 0; j < 4; ++j) {
        int mm = lane & 15;
        int pp = p0 + j*4 + (mm >> 2);
        int pos = mm & 3;
        int pr = pp / 56, pc = pp - pr*56;
        int lr = 2*pr - ohb + (pos >> 1);    // 0..3
        int ow = 2*pc + (pos & 1);
        const unsigned* xr = lx32 + ((ow & 1)*10 + lr)*184 + ((ow*3 + (ow & 1)) >> 1);

        f4v a4 = {0.f,0.f,0.f,0.f};
        #pragma unroll
        for (int ks = 0; ks < 6; ++ks) {
            int blk = ks*4 + quad;
            union { s8v v; unsigned u[4]; } av;
            av.v = (s8v){0,0,0,0,0,0,0,0};
            if (blk < 21) {
                int row = blk / 3;
                int off2 = (blk % 3) * 4;    // dwords
                const unsigned* p = xr + row*184 + off2;
                av.u[0] = p[0]; av.u[1] = p[1]; av.u[2] = p[2]; av.u[3] = p[3];
            }
            a4 = __builtin_amdgcn_mfma_f32_16x16x32_bf16(av.v, bfrag[ks], a4, 0,0,0);
        }
        acc[j] = a4;
    }

    int nlo = lane & 15;
    float bias_n = cb[nlo];
    #pragma unroll
    for (int j = 0; j < 4; ++j) {
        float* ap = (float*)&acc[j];
        float mx = fmaxf(fmaxf(ap[0], ap[1]), fmaxf(ap[2], ap[3]));
        float vv = fmaxf(mx + bias_n, 0.f);
        ((unsigned short*)pooled)[((size_t)fr*3136 + p0 + j*4 + quad)*16 + nlo] = f2bfu(vv);
    }
}

// Kernel 2 (R31): TWO fused ConvLSTM steps per dispatch.
// R30 (fused zx) verified the window model: doubling in-kernel MFMA/loads
// cost ~1us/step. R6/R8's 2-step failures are now attributable: R6 chained
// ~4.25 unstaged tiles/wave; R8's (896,4) bounds capped VGPR at 64 (spills).
// This retry: 512 thr = 8 waves, (512,2) -> 128-VGPR cap (same as the
// working single-step), <=2 serial tiles/wave.
// Block = (b, 2-row group), grid (27,8). Phase A: tiles 0..13 over rows
// y0-1..y0+2 (halo rows bit-identical to neighbor blocks), both convs per
// pixel in R30's order (5 pooled-MFMA then 5 h-MFMA); h_{t+1} (bf16) ->
// hbuf, c_{t+1} owned rows -> cbuf (LDS only; never global). Barrier.
// Phase B: tiles 0..6 over owned rows, h from hbuf (R8-verified indexing),
// pooled frame t+1 from global, c from cbuf; h_{t+2}/c_{t+2} -> global.
// Stray pooled reads for alignment-pad pixels stay inside the workspace
// (next frame / following buffers) and are discarded by the store guards.
__global__ __launch_bounds__(512, 2) void lstm_step2_fused(
    const __hip_bfloat16* __restrict__ pooled,  // [128][56][56][16] bf16
    const __hip_bfloat16* __restrict__ h_in,    // h_t  [8,54,54,16] bf16
    __hip_bfloat16* __restrict__ h_out,         // h_t+2
    const float* __restrict__ cin,              // c_t  [16][23328] planar
    float* __restrict__ cout,                   // c_t+2
    const __hip_bfloat16* __restrict__ wkb,     // [4][5][64][8] bf16
    const __hip_bfloat16* __restrict__ wrb,     // [4][5][64][8] bf16
    const float* __restrict__ bias,             // [64]
    int t)                                      // even
{
    int g  = blockIdx.x;                     // 0..26 (row pair, y0 = 2g)
    int b  = blockIdx.y;                     // 0..7
    int y0 = 2*g;
    int tid  = threadIdx.x;
    int wv   = tid >> 6;                     // 0..7
    int lane = tid & 63;
    int quad = lane >> 4;
    int ml   = lane & 15;
    int ch   = ml;

    __shared__ __align__(16) short hbuf[4][56][16];  // h_{t+1} rows y0-1..y0+2
    __shared__ float cbuf[2][54][16];                // c_{t+1} owned rows

    // Zero hbuf (448 uint4, 1/thread): OOB rows + ring cols = SAME-pad 0.
    if (tid < 448) ((uint4*)hbuf)[tid] = (uint4){0,0,0,0};

    const s8v* wkv = (const s8v*)wkb;
    const s8v* wrv = (const s8v*)wrb;
    float b_i = bias[ch], b_f = bias[16+ch], b_g = bias[32+ch], b_o = bias[48+ch];

    const __hip_bfloat16* pfA = pooled + (size_t)(b*TT + t) * (HP*WP*16);
    const __hip_bfloat16* pfB = pfA + HP*WP*16;
    const __hip_bfloat16* hb  = h_in + (size_t)b * SPIX * 16;

    __syncthreads();                          // hbuf zeros visible

    // ---------------- PHASE A: t -> t+1 on rows y0-1..y0+2 (14 tiles) ----
    int R0a = (y0 - 1) * 54;
    int ra  = R0a - (R0a & 3);               // align down (g=0: -56)
    #pragma unroll 1
    for (int ta = wv; ta < 14; ta += 8) {
        int pt0 = ta << 4;
        int rm  = ra + pt0 + ml;
        int yA, xA;
        if (rm >= 0) { yA = rm / 54; xA = rm - yA*54; } else { yA = -64; xA = 0; }

        f4v acc0 = {0.f,0.f,0.f,0.f}, acc1 = acc0, acc2 = acc0, acc3 = acc0;

        // zx part: VALID 3x3 over pooled frame t (stray reads discarded).
        #pragma unroll
        for (int ks = 0; ks < 5; ++ks) {
            int blk = ks*4 + quad;
            s8v a = (s8v){0,0,0,0,0,0,0,0};
            if ((blk < 18) & (yA >= 0)) {
                int tap = blk >> 1, half = blk & 1;
                int ky = tap / 3, kx = tap - ky*3;
                a = *(const s8v*)(pfA + ((size_t)(yA+ky)*WP + (xA+kx))*16 + half*8);
            }
            acc0 = __builtin_amdgcn_mfma_f32_16x16x32_bf16(a, wkv[(0*5+ks)*64 + lane], acc0, 0,0,0);
            acc1 = __builtin_amdgcn_mfma_f32_16x16x32_bf16(a, wkv[(1*5+ks)*64 + lane], acc1, 0,0,0);
            acc2 = __builtin_amdgcn_mfma_f32_16x16x32_bf16(a, wkv[(2*5+ks)*64 + lane], acc2, 0,0,0);
            acc3 = __builtin_amdgcn_mfma_f32_16x16x32_bf16(a, wkv[(3*5+ks)*64 + lane], acc3, 0,0,0);
        }
        // h part: SAME-pad 3x3 over h_t (global), guarded.
        #pragma unroll
        for (int ks = 0; ks < 5; ++ks) {
            int blk = ks*4 + quad;
            s8v a = (s8v){0,0,0,0,0,0,0,0};
            if (blk < 18) {
                int tap = blk >> 1, half = blk & 1;
                int ky = tap / 3, kx = tap - ky*3;
                int hy = yA + ky - 1, hx = xA + kx - 1;
                if ((hy >= 0) & (hy < HO) & (hx >= 0) & (hx < WO))
                    a = *(const s8v*)(hb + ((size_t)hy*WO + hx)*16 + half*8);
            }
            acc0 = __builtin_amdgcn_mfma_f32_16x16x32_bf16(a, wrv[(0*5+ks)*64 + lane], acc0, 0,0,0);
            acc1 = __builtin_amdgcn_mfma_f32_16x16x32_bf16(a, wrv[(1*5+ks)*64 + lane], acc1, 0,0,0);
            acc2 = __builtin_amdgcn_mfma_f32_16x16x32_bf16(a, wrv[(2*5+ks)*64 + lane], acc2, 0,0,0);
            acc3 = __builtin_amdgcn_mfma_f32_16x16x32_bf16(a, wrv[(3*5+ks)*64 + lane], acc3, 0,0,0);
        }

        // Epilogue A: c_t load (guarded), gates, stash h/c in LDS.
        int r0 = ra + pt0 + quad*4;          // multiple of 4
        float4 cold;
        if ((r0 >= 0) && (r0 + 3 < SPIX)) {
            cold = *(const float4*)&cin[(size_t)ch*NPIX + (size_t)b*SPIX + r0];
        } else {
            float* cv = (float*)&cold;
            #pragma unroll
            for (int e = 0; e < 4; ++e) {
                int re = r0 + e;
                cv[e] = ((re >= 0) & (re < SPIX))
                      ? cin[(size_t)ch*NPIX + (size_t)b*SPIX + re] : 0.f;
            }
        }
        float* a0 = (float*)&acc0; float* a1 = (float*)&acc1;
        float* a2 = (float*)&acc2; float* a3 = (float*)&acc3;
        float* co = (float*)&cold;
        #pragma unroll
        for (int reg = 0; reg < 4; ++reg) {
            float iv = hsig (a0[reg] + b_i);
            float fv = hsig (a1[reg] + b_f);
            float gv = tanhf(a2[reg] + b_g);
            float ov = hsig (a3[reg] + b_o);
            float cc = fv * co[reg] + iv * gv;
            float hv = ov * tanhf(cc);
            int rr = r0 + reg;
            if ((rr >= 0) && (rr < SPIX)) {
                int yy = rr / 54, xx = rr - yy*54;
                int lr = yy - (y0 - 1);
                if ((lr >= 0) && (lr < 4)) hbuf[lr][xx+1][ch] = (short)f2bfu(hv);
                int lc = yy - y0;
                if ((lc >= 0) && (lc < 2)) cbuf[lc][xx][ch] = cc;
            }
        }
    }
    __syncthreads();

    // ---------------- PHASE B: t+1 -> t+2 on owned rows (7 tiles) -------
    if (wv < 7) {
        int rlo = y0*54, rhi = rlo + 108;    // rlo = 108g, multiple of 4
        int pt0 = wv << 4;
        int rm  = rlo + pt0 + ml;
        int yB  = rm / 54, xB = rm - yB*54;  // pad lanes: yB up to y0+2
        int lrB = yB - y0;

        f4v acc0 = {0.f,0.f,0.f,0.f}, acc1 = acc0, acc2 = acc0, acc3 = acc0;

        // zx part: VALID 3x3 over pooled frame t+1 (stray reads discarded).
        #pragma unroll
        for (int ks = 0; ks < 5; ++ks) {
            int blk = ks*4 + quad;
            s8v a = (s8v){0,0,0,0,0,0,0,0};
            if (blk < 18) {
                int tap = blk >> 1, half = blk & 1;
                int ky = tap / 3, kx = tap - ky*3;
                a = *(const s8v*)(pfB + ((size_t)(yB+ky)*WP + (xB+kx))*16 + half*8);
            }
            acc0 = __builtin_amdgcn_mfma_f32_16x16x32_bf16(a, wkv[(0*5+ks)*64 + lane], acc0, 0,0,0);
            acc1 = __builtin_amdgcn_mfma_f32_16x16x32_bf16(a, wkv[(1*5+ks)*64 + lane], acc1, 0,0,0);
            acc2 = __builtin_amdgcn_mfma_f32_16x16x32_bf16(a, wkv[(2*5+ks)*64 + lane], acc2, 0,0,0);
            acc3 = __builtin_amdgcn_mfma_f32_16x16x32_bf16(a, wkv[(3*5+ks)*64 + lane], acc3, 0,0,0);
        }
        // h part: SAME-pad 3x3 from hbuf (R8-verified indexing).
        #pragma unroll
        for (int ks = 0; ks < 5; ++ks) {
            int blk = ks*4 + quad;
            s8v a = (s8v){0,0,0,0,0,0,0,0};
            if (blk < 18) {
                int tap = blk >> 1, half = blk & 1;
                int ky = tap / 3, kx = tap - ky*3;
                int row = lrB + ky;          // valid lanes: 0..3
                row = row > 3 ? 3 : row;     // pad lanes clamped in-bounds
                a = *(const s8v*)&hbuf[row][xB + kx][half*8];
            }
            acc0 = __builtin_amdgcn_mfma_f32_16x16x32_bf16(a, wrv[(0*5+ks)*64 + lane], acc0, 0,0,0);
            acc1 = __builtin_amdgcn_mfma_f32_16x16x32_bf16(a, wrv[(1*5+ks)*64 + lane], acc1, 0,0,0);
            acc2 = __builtin_amdgcn_mfma_f32_16x16x32_bf16(a, wrv[(2*5+ks)*64 + lane], acc2, 0,0,0);
            acc3 = __builtin_amdgcn_mfma_f32_16x16x32_bf16(a, wrv[(3*5+ks)*64 + lane], acc3, 0,0,0);
        }

        // Epilogue B: c from cbuf, write h_{t+2}/c_{t+2} to global.
        int r0 = rlo + pt0 + quad*4;
        float* a0 = (float*)&acc0; float* a1 = (float*)&acc1;
        float* a2 = (float*)&acc2; float* a3 = (float*)&acc3;
        #pragma unroll
        for (int reg = 0; reg < 4; ++reg) {
            int rr = r0 + reg;
            if (rr < rhi) {
                int yy = rr / 54, xx = rr - yy*54;
                float cold = cbuf[yy - y0][xx][ch];
                float iv = hsig (a0[reg] + b_i);
                float fv = hsig (a1[reg] + b_f);
                float gv = tanhf(a2[reg] + b_g);
                float ov = hsig (a3[reg] + b_o);
                float cc = fv * cold + iv * gv;
                float hv = ov * tanhf(cc);
                cout[(size_t)ch*NPIX + (size_t)b*SPIX + rr] = cc;
                ((unsigned short*)h_out)[((size_t)b*SPIX + rr)*16 + ch] = f2bfu(hv);
            }
        }
    }
}

// Kernel 3: spatial mean (bf16 h) -> dense(16->6) -> softmax. One block per b.
// R18: short8 loads, 1024 threads, parity-preserving LDS tree (verified win).
__global__ __launch_bounds__(1024) void head_kernel(
    const __hip_bfloat16* __restrict__ h,   // [8,54,54,16] bf16
    const float* __restrict__ dw,   // [16,6]
    const float* __restrict__ db,   // [6]
    float* __restrict__ out)        // [8,6]
{
    int b = blockIdx.x;
    int tid = threadIdx.x;
    const s8v* hb = (const s8v*)(h + (size_t)b * SPIX * 16);  // 5832 s8v per b

    float acc[8] = {0.f,0.f,0.f,0.f,0.f,0.f,0.f,0.f};
    for (int j = tid; j < SPIX*2; j += 1024) {
        s8v v = hb[j];
        #pragma unroll
        for (int k = 0; k < 8; ++k) acc[k] += bf2f((unsigned short)v[k]);
    }

    __shared__ float red[1024][8];           // 32 KB
    #pragma unroll
    for (int k = 0; k < 8; ++k) red[tid][k] = acc[k];
    __syncthreads();
    for (int st = 512; st >= 2; st >>= 1) {
        if (tid < st) {
            #pragma unroll
            for (int k = 0; k < 8; ++k) red[tid][k] += red[tid + st][k];
        }
        __syncthreads();
    }

    __shared__ float logits[8];
    if (tid < NC) {
        float l = db[tid];
        #pragma unroll
        for (int k = 0; k < 8; ++k) {
            l += (red[0][k] * (1.0f/2916.0f)) * dw[k*NC + tid];
            l += (red[1][k] * (1.0f/2916.0f)) * dw[(8+k)*NC + tid];
        }
        logits[tid] = l;
    }
    __syncthreads();
    if (tid < NC) {
        float m = -1e30f;
        for (int k = 0; k < NC; ++k) m = fmaxf(m, logits[k]);
        float e = expf(logits[tid] - m);
        float d = 0.0f;
        for (int k = 0; k < NC; ++k) d += expf(logits[k] - m);
        out[b*NC + tid] = e / d;
    }
}

extern "C" void kernel_launch(void* const* d_in, const int* in_sizes, int n_in,
                              void* d_out, int out_size, void* d_ws, size_t ws_size,
                              hipStream_t stream) {
    const float* x      = (const float*)d_in[0];
    const float* conv_w = (const float*)d_in[1];
    const float* conv_b = (const float*)d_in[2];
    const float* wk     = (const float*)d_in[3];
    const float* wr     = (const float*)d_in[4];
    const float* bias   = (const float*)d_in[5];
    const float* dw     = (const float*)d_in[6];
    const float* db     = (const float*)d_in[7];
    float* out = (float*)d_out;

    char* base = (char*)d_ws;
    __hip_bfloat16* pooled = (__hip_bfloat16*)base;                 // 12.85 MB
    __hip_bfloat16* hA  = pooled + POOLED_BF16;                     // 746 KB
    __hip_bfloat16* hB  = hA + NPIX*16;
    __hip_bfloat16* wkb = hB + NPIX*16;                             // 20 KB
    __hip_bfloat16* wrb = wkb + 10240;                              // 20 KB
    __hip_bfloat16* cwb = wrb + 10240;                              // 6 KB
    float* cA = (float*)(cwb + 3072);                               // 1.49 MB
    float* cB = cA + NPIX*16;                                       // 1.49 MB
    // xpad parity copies follow (zx buffer deleted since R30).
    __hip_bfloat16* xp0 = (__hip_bfloat16*)(cB + NPIX*16);          // 10.9 MB
    __hip_bfloat16* xp1 = xp0 + XPAD_ELEMS;                         // 10.9 MB

    // One prep dispatch: xpad + wk/wr/cw prepack + c0/h0 zero.
    prep_kernel<<<dim3(5950), dim3(256), 0, stream>>>(
        x, xp0, xp1, wk, wkb, wr, wrb, conv_w, cwb, cA, hA);
    conv_mfma_kernel<<<dim3(49, 128), dim3(256), 0, stream>>>(xp0, xp1, cwb, conv_b, pooled);

    // 8 dispatches, 2 fused time-steps each.
    for (int k = 0; k < 8; ++k) {
        const __hip_bfloat16* hin  = (k & 1) ? hB : hA;
        __hip_bfloat16*       hout = (k & 1) ? hA : hB;
        const float* ci = (k & 1) ? cB : cA;
        float*       co = (k & 1) ? cA : cB;
        lstm_step2_fused<<<dim3(27, 8), dim3(512), 0, stream>>>(
            pooled, hin, hout, ci, co, wkb, wrb, bias, 2*k);
    }
    // k=7 wrote hA (h16)
    head_kernel<<<dim3(8), dim3(1024), 0, stream>>>(hA, dw, db, out);
}

// Round 15
// 233.591 us; speedup vs baseline: 1.0915x; 1.0915x over previous
//
#include <hip/hip_runtime.h>
#include <hip/hip_bf16.h>
#include <math.h>

// Problem dims
#define BB 8
#define TT 16
#define HH 112
#define WW 112
#define CC 3
#define FF 16
#define HP 56
#define WP 56
#define HO 54
#define WO 54
#define NC 6

#define NPIX (BB*HO*WO)               // 23328
#define SPIX (HO*WO)                  // 2916
#define POOLED_BF16  (128*56*56*16)   // 6,422,528 bf16

// xpad: per-frame bf16 rows with halo + pad: 118 rows x 360 elems
#define XROW 360
#define XFRM (118*XROW)               // 42,480
#define XPAD_ELEMS (128*XFRM)         // 5,437,440 per parity copy

typedef __attribute__((ext_vector_type(8))) short s8v;   // 8 bf16 (4 VGPRs)
typedef __attribute__((ext_vector_type(4))) float f4v;   // MFMA acc

__device__ __forceinline__ float hsig(float x) {
    return fminf(fmaxf(0.2f*x + 0.5f, 0.0f), 1.0f);
}
__device__ __forceinline__ unsigned pk2(float lo, float hi) {
    union { __hip_bfloat16 h; unsigned short u; } a, b;
    a.h = __float2bfloat16(lo); b.h = __float2bfloat16(hi);
    return ((unsigned)b.u << 16) | (unsigned)a.u;
}
__device__ __forceinline__ float bf2f(unsigned short u) {
    union { unsigned v; float f; } x; x.v = ((unsigned)u) << 16; return x.f;
}
__device__ __forceinline__ unsigned short f2bfu(float f) {
    union { __hip_bfloat16 h; unsigned short u; } v;
    v.h = __float2bfloat16(f); return v.u;
}

// ---------- prep job bodies (verbatim logic, virtual block id) ----------
__device__ __forceinline__ void w_prepack_body(int vb, const float* __restrict__ w,
                                               __hip_bfloat16* __restrict__ wb)
{
    int i = vb * 256 + threadIdx.x;                // 40*256 = 10240 exact
    int j    = i & 7;
    int lane = (i >> 3) & 63;
    int ks   = (i >> 9) % 5;
    int nt   = (i >> 9) / 5;
    int k = ks*32 + ((lane >> 4) & 3)*8 + j;
    int n = nt*16 + (lane & 15);
    float v = 0.f;
    if (k < 144) {
        int tap = k >> 4, ci = k & 15;
        v = w[tap*1024 + ci*64 + n];
    }
    wb[i] = __float2bfloat16(v);
}

__device__ __forceinline__ void cw_prepack_body(int vb, const float* __restrict__ cw,
                                                __hip_bfloat16* __restrict__ cwb)
{
    int i = vb * 256 + threadIdx.x;                // 12*256 = 3072 exact
    int j    = i & 7;
    int lane = (i >> 3) & 63;
    int ks   = i >> 9;                             // 0..5
    int k = ks*32 + ((lane >> 4) & 3)*8 + j;
    int n = lane & 15;
    float v = 0.f;
    if (k < 168) {
        int row = k / 24, idx = k % 24;
        if (idx < 21) {
            int kx = idx / 3, ci = idx % 3;
            v = cw[((row*7 + kx)*3 + ci)*16 + n];
        }
    }
    cwb[i] = __float2bfloat16(v);
}

__device__ __forceinline__ void xpad_body(int vb, const float* __restrict__ x,
                                          __hip_bfloat16* __restrict__ xp0,
                                          __hip_bfloat16* __restrict__ xp1)
{
    int idx = vb * 256 + threadIdx.x;              // 5310*256 = 1,359,360 exact
    int e4 = idx % 90;
    int rr = (idx / 90) % 118;
    int fr = idx / (90*118);
    int e0 = e4 * 4;
    int ir = rr - 3;
    const float* xf = x + (size_t)fr * (112*336);
    bool rowok = (ir >= 0) & (ir < 112);

    float v[5];
    #pragma unroll
    for (int i = 0; i < 5; ++i) {
        int s = e0 - 1 + i;
        bool ok = rowok & (s >= 9) & (s < 345);
        v[i] = ok ? xf[ir*336 + (s - 9)] : 0.f;
    }
    size_t o = ((size_t)fr*118 + rr) * XROW + e0;
    uint2 a0, a1;
    a0.x = pk2(v[1], v[2]); a0.y = pk2(v[3], v[4]);
    a1.x = pk2(v[0], v[1]); a1.y = pk2(v[2], v[3]);
    *(uint2*)&xp0[o] = a0;
    *(uint2*)&xp1[o] = a1;
}

// Kernel 0 (R26, kept): ALL independent prep work in ONE dispatch.
__global__ __launch_bounds__(256) void prep_kernel(
    const float* __restrict__ x,
    __hip_bfloat16* __restrict__ xp0, __hip_bfloat16* __restrict__ xp1,
    const float* __restrict__ wk, __hip_bfloat16* __restrict__ wkb,
    const float* __restrict__ wr, __hip_bfloat16* __restrict__ wrb,
    const float* __restrict__ cw, __hip_bfloat16* __restrict__ cwb,
    float* __restrict__ cpl, __hip_bfloat16* __restrict__ hA)
{
    int bid = blockIdx.x;
    if (bid < 5310) { xpad_body(bid, x, xp0, xp1); return; }
    bid -= 5310;
    if (bid < 40) { w_prepack_body(bid, wk, wkb); return; }
    bid -= 40;
    if (bid < 40) { w_prepack_body(bid, wr, wrb); return; }
    bid -= 40;
    if (bid < 12) { cw_prepack_body(bid, cw, cwb); return; }
    bid -= 12;
    if (bid < 365) {                               // c0 = 0
        int u = bid*256 + threadIdx.x;
        if (u < 93312) ((uint4*)cpl)[u] = (uint4){0,0,0,0};
        return;
    }
    bid -= 365;
    {                                              // h0 = 0
        int u = bid*256 + threadIdx.x;
        if (u < 46656) ((uint4*)hA)[u] = (uint4){0,0,0,0};
    }
}

// Kernel 1: conv 7x7 + bias + relu + maxpool via MFMA.
// R20: LDS-staged input rows (verified win: 47.6 -> ~15 us).
__global__ __launch_bounds__(256, 6) void conv_mfma_kernel(
    const __hip_bfloat16* __restrict__ xp0,
    const __hip_bfloat16* __restrict__ xp1,
    const __hip_bfloat16* __restrict__ cwb,  // [6][64][8]
    const float* __restrict__ cb,            // [16]
    __hip_bfloat16* __restrict__ pooled)     // [128,56,56,16] bf16
{
    int wv = threadIdx.x >> 6;
    int lane = threadIdx.x & 63;
    int quad = lane >> 4;
    int fr = blockIdx.y;
    int p0b = blockIdx.x * 64;               // block's pooled px base
    int p0 = p0b + wv * 16;                  // wave's pooled px base

    __shared__ short lx[2][10][368];         // 14,720 B
    int pr0 = p0b / 56;
    int ohb = 2 * pr0;                       // first staged input row
    {
        const __hip_bfloat16* s0 = xp0 + (size_t)fr*XFRM + (size_t)ohb*XROW;
        const __hip_bfloat16* s1 = xp1 + (size_t)fr*XFRM + (size_t)ohb*XROW;
        for (int u = threadIdx.x; u < 900; u += 256) {
            int par = u / 450;
            int rem = u - par*450;
            int rr  = rem / 45;
            int c   = rem - rr*45;           // 16B unit within row
            const __hip_bfloat16* s = (par ? s1 : s0) + rr*XROW + c*8;
            *(uint4*)&lx[par][rr][c*8] = *(const uint4*)s;
        }
    }
    __syncthreads();

    const s8v* wbp = (const s8v*)cwb;
    s8v bfrag[6];
    #pragma unroll
    for (int ks = 0; ks < 6; ++ks) bfrag[ks] = wbp[ks*64 + lane];

    const unsigned* lx32 = (const unsigned*)&lx[0][0][0];

    f4v acc[4];
    #pragma unroll
    for (int j = 0; j < 4; ++j) {
        int mm = lane & 15;
        int pp = p0 + j*4 + (mm >> 2);
        int pos = mm & 3;
        int pr = pp / 56, pc = pp - pr*56;
        int lr = 2*pr - ohb + (pos >> 1);    // 0..3
        int ow = 2*pc + (pos & 1);
        const unsigned* xr = lx32 + ((ow & 1)*10 + lr)*184 + ((ow*3 + (ow & 1)) >> 1);

        f4v a4 = {0.f,0.f,0.f,0.f};
        #pragma unroll
        for (int ks = 0; ks < 6; ++ks) {
            int blk = ks*4 + quad;
            union { s8v v; unsigned u[4]; } av;
            av.v = (s8v){0,0,0,0,0,0,0,0};
            if (blk < 21) {
                int row = blk / 3;
                int off2 = (blk % 3) * 4;    // dwords
                const unsigned* p = xr + row*184 + off2;
                av.u[0] = p[0]; av.u[1] = p[1]; av.u[2] = p[2]; av.u[3] = p[3];
            }
            a4 = __builtin_amdgcn_mfma_f32_16x16x32_bf16(av.v, bfrag[ks], a4, 0,0,0);
        }
        acc[j] = a4;
    }

    int nlo = lane & 15;
    float bias_n = cb[nlo];
    #pragma unroll
    for (int j = 0; j < 4; ++j) {
        float* ap = (float*)&acc[j];
        float mx = fmaxf(fmaxf(ap[0], ap[1]), fmaxf(ap[2], ap[3]));
        float vv = fmaxf(mx + bias_n, 0.f);
        ((unsigned short*)pooled)[((size_t)fr*3136 + p0 + j*4 + quad)*16 + nlo] = f2bfu(vv);
    }
}

// Kernel 2 (R30, FINAL): FUSED ConvLSTM step — zx-conv + h-conv + gates in
// ONE kernel; zx_mfma and the 47.8MB zx buffer deleted. Both convs target
// the SAME accumulator layout (acc0..3 = i/f/g/o for 4 px, ch = lane&15):
// 5 MFMA pooled-taps x wkb (VALID) + 5 MFMA h-taps x wrb (SAME pad).
// Scan-floor evidence (9 variants): per-step ~12.5-13us invariant to
// occupancy (5.7->23 w/CU), load count/pattern, VGPR, LDS staging, and
// 2-step fusion (3 attempts: 31/33.6/27us per pair >= 2 dispatches);
// persistent kernels pay ~65us/step cross-XCD coherence. This is the
// serial-recurrence execution floor at this problem size.
__global__ __launch_bounds__(256, 2) void lstm_step_fused(
    const __hip_bfloat16* __restrict__ pooled,  // [128][56][56][16] bf16
    const __hip_bfloat16* __restrict__ h_in,    // [8,54,54,16] bf16
    __hip_bfloat16* __restrict__ h_out,
    float* __restrict__ cpl,                    // [16][23328] planar fp32
    const __hip_bfloat16* __restrict__ wkb,     // [4][5][64][8] bf16
    const __hip_bfloat16* __restrict__ wrb,     // [4][5][64][8] bf16
    const float* __restrict__ bias,             // [64]
    int t)
{
    int wid = (blockIdx.x << 2) + (threadIdx.x >> 6);
    if (wid >= 1458) return;                 // no barriers below
    int lane = threadIdx.x & 63;
    int quad = lane >> 4;
    int pt0  = wid << 4;
    int m    = pt0 + (lane & 15);

    int b  = m / SPIX;
    int r  = m % SPIX;
    int oh = r / WO, ow = r % WO;
    const __hip_bfloat16* pf = pooled + (size_t)(b*TT + t) * (HP*WP*16);
    const __hip_bfloat16* hb = h_in + (size_t)b * SPIX * 16;

    f4v acc0 = {0.f,0.f,0.f,0.f}, acc1 = acc0, acc2 = acc0, acc3 = acc0;
    const s8v* wkv = (const s8v*)wkb;
    const s8v* wrv = (const s8v*)wrb;

    // ---- zx part: VALID 3x3 conv over pooled (56x56), no guards ----
    #pragma unroll
    for (int ks = 0; ks < 5; ++ks) {
        int blk = ks*4 + quad;
        s8v a = (s8v){0,0,0,0,0,0,0,0};
        if (blk < 18) {
            int tap = blk >> 1, half = blk & 1;
            int ky = tap / 3, kx = tap - ky*3;
            a = *(const s8v*)(pf + ((size_t)(oh+ky)*WP + (ow+kx))*16 + half*8);
        }
        acc0 = __builtin_amdgcn_mfma_f32_16x16x32_bf16(a, wkv[(0*5+ks)*64 + lane], acc0, 0,0,0);
        acc1 = __builtin_amdgcn_mfma_f32_16x16x32_bf16(a, wkv[(1*5+ks)*64 + lane], acc1, 0,0,0);
        acc2 = __builtin_amdgcn_mfma_f32_16x16x32_bf16(a, wkv[(2*5+ks)*64 + lane], acc2, 0,0,0);
        acc3 = __builtin_amdgcn_mfma_f32_16x16x32_bf16(a, wkv[(3*5+ks)*64 + lane], acc3, 0,0,0);
    }

    // ---- h part: SAME-pad 3x3 conv over h_in (54x54), guarded ----
    #pragma unroll
    for (int ks = 0; ks < 5; ++ks) {
        int blk = ks*4 + quad;
        s8v a = (s8v){0,0,0,0,0,0,0,0};
        if (blk < 18) {
            int tap = blk >> 1, half = blk & 1;
            int ky = tap / 3, kx = tap - ky*3;
            int hy = oh + ky - 1, hx = ow + kx - 1;   // SAME pad
            if ((hy >= 0) & (hy < HO) & (hx >= 0) & (hx < WO))
                a = *(const s8v*)(hb + ((size_t)hy*WO + hx)*16 + half*8);
        }
        acc0 = __builtin_amdgcn_mfma_f32_16x16x32_bf16(a, wrv[(0*5+ks)*64 + lane], acc0, 0,0,0);
        acc1 = __builtin_amdgcn_mfma_f32_16x16x32_bf16(a, wrv[(1*5+ks)*64 + lane], acc1, 0,0,0);
        acc2 = __builtin_amdgcn_mfma_f32_16x16x32_bf16(a, wrv[(2*5+ks)*64 + lane], acc2, 0,0,0);
        acc3 = __builtin_amdgcn_mfma_f32_16x16x32_bf16(a, wrv[(3*5+ks)*64 + lane], acc3, 0,0,0);
    }

    // Epilogue: lane owns channel ch for pixels pm..pm+3 (one b: 2916%4==0).
    int ch = lane & 15;
    int pm = pt0 + quad*4;

    float4 cold = *(float4*)&cpl[(size_t)ch * NPIX + pm];
    float b_i = bias[ch], b_f = bias[16+ch], b_g = bias[32+ch], b_o = bias[48+ch];

    float4 cnew;
    unsigned short hn[4];
    float* co = &cold.x; float* cn = &cnew.x;
    float* a0 = (float*)&acc0; float* a1 = (float*)&acc1;
    float* a2 = (float*)&acc2; float* a3 = (float*)&acc3;
    #pragma unroll
    for (int reg = 0; reg < 4; ++reg) {
        float iv = hsig (a0[reg] + b_i);
        float fv = hsig (a1[reg] + b_f);
        float gv = tanhf(a2[reg] + b_g);
        float ov = hsig (a3[reg] + b_o);
        float cc = fv * co[reg] + iv * gv;
        cn[reg] = cc;
        hn[reg] = f2bfu(ov * tanhf(cc));
    }
    *(float4*)&cpl[(size_t)ch * NPIX + pm] = cnew;
    #pragma unroll
    for (int reg = 0; reg < 4; ++reg)
        ((unsigned short*)h_out)[(size_t)(pm + reg) * 16 + ch] = hn[reg];
}

// Kernel 3: spatial mean (bf16 h) -> dense(16->6) -> softmax. One block per b.
// R18: short8 loads, 1024 threads, parity-preserving LDS tree (verified win).
__global__ __launch_bounds__(1024) void head_kernel(
    const __hip_bfloat16* __restrict__ h,   // [8,54,54,16] bf16
    const float* __restrict__ dw,   // [16,6]
    const float* __restrict__ db,   // [6]
    float* __restrict__ out)        // [8,6]
{
    int b = blockIdx.x;
    int tid = threadIdx.x;
    const s8v* hb = (const s8v*)(h + (size_t)b * SPIX * 16);  // 5832 s8v per b

    float acc[8] = {0.f,0.f,0.f,0.f,0.f,0.f,0.f,0.f};
    for (int j = tid; j < SPIX*2; j += 1024) {
        s8v v = hb[j];
        #pragma unroll
        for (int k = 0; k < 8; ++k) acc[k] += bf2f((unsigned short)v[k]);
    }

    __shared__ float red[1024][8];           // 32 KB
    #pragma unroll
    for (int k = 0; k < 8; ++k) red[tid][k] = acc[k];
    __syncthreads();
    for (int st = 512; st >= 2; st >>= 1) {
        if (tid < st) {
            #pragma unroll
            for (int k = 0; k < 8; ++k) red[tid][k] += red[tid + st][k];
        }
        __syncthreads();
    }

    __shared__ float logits[8];
    if (tid < NC) {
        float l = db[tid];
        #pragma unroll
        for (int k = 0; k < 8; ++k) {
            l += (red[0][k] * (1.0f/2916.0f)) * dw[k*NC + tid];
            l += (red[1][k] * (1.0f/2916.0f)) * dw[(8+k)*NC + tid];
        }
        logits[tid] = l;
    }
    __syncthreads();
    if (tid < NC) {
        float m = -1e30f;
        for (int k = 0; k < NC; ++k) m = fmaxf(m, logits[k]);
        float e = expf(logits[tid] - m);
        float d = 0.0f;
        for (int k = 0; k < NC; ++k) d += expf(logits[k] - m);
        out[b*NC + tid] = e / d;
    }
}

extern "C" void kernel_launch(void* const* d_in, const int* in_sizes, int n_in,
                              void* d_out, int out_size, void* d_ws, size_t ws_size,
                              hipStream_t stream) {
    const float* x      = (const float*)d_in[0];
    const float* conv_w = (const float*)d_in[1];
    const float* conv_b = (const float*)d_in[2];
    const float* wk     = (const float*)d_in[3];
    const float* wr     = (const float*)d_in[4];
    const float* bias   = (const float*)d_in[5];
    const float* dw     = (const float*)d_in[6];
    const float* db     = (const float*)d_in[7];
    float* out = (float*)d_out;

    char* base = (char*)d_ws;
    __hip_bfloat16* pooled = (__hip_bfloat16*)base;                 // 12.85 MB
    __hip_bfloat16* hA  = pooled + POOLED_BF16;                     // 746 KB
    __hip_bfloat16* hB  = hA + NPIX*16;
    __hip_bfloat16* wkb = hB + NPIX*16;                             // 20 KB
    __hip_bfloat16* wrb = wkb + 10240;                              // 20 KB
    __hip_bfloat16* cwb = wrb + 10240;                              // 6 KB
    float* cpl = (float*)(cwb + 3072);                              // 1.49 MB
    // xpad parity copies live where zx used to (zx deleted since R30).
    __hip_bfloat16* xp0 = (__hip_bfloat16*)(cpl + NPIX*16);         // 10.9 MB
    __hip_bfloat16* xp1 = xp0 + XPAD_ELEMS;                         // 10.9 MB

    // One prep dispatch: xpad + wk/wr/cw prepack + c0/h0 zero.
    prep_kernel<<<dim3(5950), dim3(256), 0, stream>>>(
        x, xp0, xp1, wk, wkb, wr, wrb, conv_w, cwb, cpl, hA);
    conv_mfma_kernel<<<dim3(49, 128), dim3(256), 0, stream>>>(xp0, xp1, cwb, conv_b, pooled);

    for (int t = 0; t < TT; ++t) {
        const __hip_bfloat16* hin  = (t & 1) ? hB : hA;
        __hip_bfloat16*       hout = (t & 1) ? hA : hB;
        lstm_step_fused<<<dim3(365), dim3(256), 0, stream>>>(
            pooled, hin, hout, cpl, wkb, wrb, bias, t);
    }
    // t=15 (odd) wrote hA
    head_kernel<<<dim3(8), dim3(1024), 0, stream>>>(hA, dw, db, out);
}